// Round 3
// baseline (1725.572 us; speedup 1.0000x reference)
//
#include <hip/hip_runtime.h>

#define N_NODES 10000
#define N_EDGES 160000
#define NUM_FEAT 14
#define EDGE_DIM 4
#define DIM 64
#define HID 128
#define LAYERS 28

#define NEG_INF (-__builtin_inff())

// ---------------- CSR build ----------------

__global__ __launch_bounds__(256) void k_zero(int* __restrict__ p, int n) {
  int i = blockIdx.x * 256 + threadIdx.x;
  if (i < n) p[i] = 0;
}

__global__ __launch_bounds__(256) void k_hist(const int* __restrict__ dst, int* __restrict__ cur) {
  int e = blockIdx.x * 256 + threadIdx.x;
  if (e < N_EDGES) atomicAdd(&cur[dst[e]], 1);
}

// single block, 256 threads: exclusive scan of degrees -> off[0..N], cur[i]=off[i]
__global__ __launch_bounds__(256) void k_scan(int* __restrict__ cur, int* __restrict__ off) {
  __shared__ int part[256];
  int t = threadIdx.x;
  const int CH = 40;  // 256*40 = 10240 >= N_NODES
  int base = t * CH;
  int s = 0;
  for (int i = 0; i < CH; i++) {
    int idx = base + i;
    if (idx < N_NODES) s += cur[idx];
  }
  part[t] = s;
  __syncthreads();
  for (int ofs = 1; ofs < 256; ofs <<= 1) {
    int tmp = (t >= ofs) ? part[t - ofs] : 0;
    __syncthreads();
    part[t] += tmp;
    __syncthreads();
  }
  int run = part[t] - s;  // exclusive prefix of this chunk
  for (int i = 0; i < CH; i++) {
    int idx = base + i;
    if (idx < N_NODES) {
      int d = cur[idx];
      off[idx] = run;
      cur[idx] = run;
      run += d;
    }
  }
  if (t == 255) off[N_NODES] = part[255];
}

__global__ __launch_bounds__(256) void k_scatter(const int* __restrict__ dst, int* __restrict__ cur,
                                                 int* __restrict__ eids) {
  int e = blockIdx.x * 256 + threadIdx.x;
  if (e < N_EDGES) {
    int p = atomicAdd(&cur[dst[e]], 1);
    eids[p] = e;
  }
}

// Deterministic order without serial sort: wave-per-node bitonic sort of edge ids
// (64 lanes, shfl_xor), then gather src/eattr into CSR-slot order once.
__global__ __launch_bounds__(256) void k_sortgather(
    const int* __restrict__ off, const int* __restrict__ eids,
    const int* __restrict__ src, const float4* __restrict__ eattr,
    int* __restrict__ src_s, float4* __restrict__ eattr_s) {
  int node = blockIdx.x * 4 + (threadIdx.x >> 6);
  int lane = threadIdx.x & 63;
  if (node >= N_NODES) return;
  int a = off[node];
  int d = off[node + 1] - a;
  if (d <= 64) {
    int key = (lane < d) ? eids[a + lane] : 0x7fffffff;
#pragma unroll
    for (int k = 2; k <= 64; k <<= 1) {
      for (int j = k >> 1; j > 0; j >>= 1) {
        int p = __shfl_xor(key, j);
        bool dirUp = ((lane & k) == 0);
        bool isLower = ((lane & j) == 0);
        key = ((isLower == dirUp) ? min(key, p) : max(key, p));
      }
    }
    if (lane < d) {
      int e = key;
      src_s[a + lane] = src[e];
      eattr_s[a + lane] = eattr[e];
    }
  } else {
    // rare fallback: counting rank (edge ids unique -> exact, deterministic)
    for (int i = lane; i < d; i += 64) {
      int e = eids[a + i];
      int r = 0;
      for (int j = 0; j < d; j++) r += (eids[a + j] < e) ? 1 : 0;
      src_s[a + r] = src[e];
      eattr_s[a + r] = eattr[e];
    }
  }
}

// ---------------- node encoder ----------------

__global__ __launch_bounds__(256) void k_enc(const float* __restrict__ x, const float* __restrict__ Wn,
                                             const float* __restrict__ bn, float* __restrict__ hc,
                                             float* __restrict__ u) {
  int gid = blockIdx.x * 256 + threadIdx.x;
  if (gid >= N_NODES * DIM) return;
  int n = gid >> 6, j = gid & 63;
  float acc = bn[j];
#pragma unroll
  for (int k = 0; k < NUM_FEAT; k++) acc += x[n * NUM_FEAT + k] * Wn[k * DIM + j];
  hc[gid] = acc;
  u[gid] = acc;
}

// ---------------- fused layer kernel ----------------
// One block = 16 nodes. Phase 1: per-wave online-softmax edge aggregation
// (lane = feature) for 4 nodes/wave, result -> LDS transposed. Phase 2:
// GEMM1 + LN + relu + GEMM2 + residual + (optional) next-layer pre-LN.
// Weights read from global (L1-resident). u double-buffered across layers.

#define TILE 16
#define NBLK (N_NODES / TILE)   // 625, exact

__global__ __launch_bounds__(256) void k_layer(
    const float* __restrict__ uin, float* __restrict__ hc, float* __restrict__ uout,
    const float4* __restrict__ eattr_s, const int* __restrict__ src_s,
    const int* __restrict__ off,
    const float* __restrict__ W_edge, const float* __restrict__ b_edge,
    const float* __restrict__ tptr, int layer,
    const float* __restrict__ W1, const float* __restrict__ b1,
    const float* __restrict__ g1, const float* __restrict__ be1,
    const float* __restrict__ W2, const float* __restrict__ b2,
    const float* __restrict__ lng, const float* __restrict__ lnb,
    int addRes, int writeU) {
  __shared__ float sT[128 * 20];  // rows 0..63: hT[k][n]; later rows 0..127: zT[j][n]
  __shared__ float sPs[32 * 16];
  __shared__ float sPq[32 * 16];
  __shared__ float sMu[TILE], sRs[TILE];

  int tid = threadIdx.x;
  int lane = tid & 63;
  int wv = tid >> 6;  // wave 0..3
  int t0 = blockIdx.x * TILE;

  // ---- phase 1: edge aggregation, 4 nodes per wave ----
  {
    float tvv = tptr[layer];
    float w0 = W_edge[lane], w1 = W_edge[64 + lane], w2 = W_edge[128 + lane],
          w3 = W_edge[192 + lane];
    float be = b_edge[lane];
    for (int q = 0; q < 4; q++) {
      int n = wv * 4 + q;  // 0..15
      int gn = t0 + n;
      int a = off[gn], d = off[gn + 1] - a;
      float un = uin[(gn << 6) + lane];
      float m = NEG_INF, sum = 0.f, acc = 0.f;
      for (int i = 0; i < d; i += 16) {
        int b = min(16, d - i);
        float msg[16];
#pragma unroll
        for (int j = 0; j < 16; j++) {
          if (j < b) {
            int sn = src_s[a + i + j];
            float4 ev = eattr_s[a + i + j];
            msg[j] = fmaxf(uin[(sn << 6) + lane] + be + ev.x * w0 + ev.y * w1 +
                           ev.z * w2 + ev.w * w3, 0.f) + 1e-7f;
          }
        }
#pragma unroll
        for (int j = 0; j < 16; j++) {
          if (j < b) {
            float lg = msg[j] * tvv;
            float mn = fmaxf(m, lg);
            float sc = __expf(m - mn);  // exp(-inf)=0 on first edge
            float ew = __expf(lg - mn);
            sum = sum * sc + ew;
            acc = acc * sc + ew * msg[j];
            m = mn;
          }
        }
      }
      sT[lane * 20 + n] = acc / (sum + 1e-16f) + un;  // h1 = agg + x
    }
  }
  __syncthreads();  // B0: hT ready

  int n0 = (tid & 7) * 2;  // 2 nodes per thread
  int jg = tid >> 3;       // 0..31
  int j0 = jg * 4;         // GEMM1 cols
  int o0 = jg * 2;         // GEMM2 cols

  // ---- GEMM1: acc[2 nodes][4 hid] ----
  float4 b1v = *((const float4*)&b1[j0]);
  float acc[2][4];
#pragma unroll
  for (int q = 0; q < 2; q++) {
    acc[q][0] = b1v.x; acc[q][1] = b1v.y; acc[q][2] = b1v.z; acc[q][3] = b1v.w;
  }
#pragma unroll 4
  for (int k = 0; k < 64; k++) {
    float2 hv = *((float2*)&sT[k * 20 + n0]);
    float4 wv4 = *((const float4*)&W1[k * 128 + j0]);
    float h_[2] = {hv.x, hv.y};
    float w_[4] = {wv4.x, wv4.y, wv4.z, wv4.w};
#pragma unroll
    for (int q = 0; q < 2; q++)
#pragma unroll
      for (int p = 0; p < 4; p++) acc[q][p] += h_[q] * w_[p];
  }

  // ---- LN1 partials ----
#pragma unroll
  for (int q = 0; q < 2; q++) {
    sPs[jg * 16 + n0 + q] = acc[q][0] + acc[q][1] + acc[q][2] + acc[q][3];
    sPq[jg * 16 + n0 + q] = acc[q][0] * acc[q][0] + acc[q][1] * acc[q][1] +
                            acc[q][2] * acc[q][2] + acc[q][3] * acc[q][3];
  }
  __syncthreads();  // B1
  if (tid < TILE) {
    float s = 0.f, qq = 0.f;
    for (int g = 0; g < 32; g++) { s += sPs[g * 16 + tid]; qq += sPq[g * 16 + tid]; }
    float mu = s * (1.f / 128.f);
    float var = qq * (1.f / 128.f) - mu * mu;
    sMu[tid] = mu;
    sRs[tid] = rsqrtf(var + 1e-5f);
  }
  __syncthreads();  // B2: stats ready; all GEMM1 h-reads done -> sT reusable

  // ---- LN1 apply + relu -> zT[j][n] ----
  {
    float4 gv = *((const float4*)&g1[j0]);
    float4 bev = *((const float4*)&be1[j0]);
    float g_[4] = {gv.x, gv.y, gv.z, gv.w};
    float be_[4] = {bev.x, bev.y, bev.z, bev.w};
    float mu0 = sMu[n0], rs0 = sRs[n0];
    float mu1 = sMu[n0 + 1], rs1 = sRs[n0 + 1];
#pragma unroll
    for (int p = 0; p < 4; p++) {
      float2 zv;
      zv.x = fmaxf((acc[0][p] - mu0) * rs0 * g_[p] + be_[p], 0.f);
      zv.y = fmaxf((acc[1][p] - mu1) * rs1 * g_[p] + be_[p], 0.f);
      *((float2*)&sT[(j0 + p) * 20 + n0]) = zv;
    }
  }
  __syncthreads();  // B3: zT ready

  // ---- GEMM2: o[2 nodes][2 out] ----
  float2 b2v = *((const float2*)&b2[o0]);
  float o_[2][2];
#pragma unroll
  for (int q = 0; q < 2; q++) { o_[q][0] = b2v.x; o_[q][1] = b2v.y; }
#pragma unroll 4
  for (int k = 0; k < 128; k++) {
    float2 zv = *((float2*)&sT[k * 20 + n0]);
    float2 wv2 = *((const float2*)&W2[k * 64 + o0]);
#pragma unroll
    for (int q = 0; q < 2; q++) {
      float z = (q == 0) ? zv.x : zv.y;
      o_[q][0] += z * wv2.x;
      o_[q][1] += z * wv2.y;
    }
  }

  // ---- residual + hc write ----
  float hcn[2][2];
#pragma unroll
  for (int q = 0; q < 2; q++) {
    int gn = t0 + n0 + q;
    float2 r = addRes ? *((const float2*)&hc[gn * 64 + o0]) : make_float2(0.f, 0.f);
    hcn[q][0] = o_[q][0] + r.x;
    hcn[q][1] = o_[q][1] + r.y;
    *((float2*)&hc[gn * 64 + o0]) = make_float2(hcn[q][0], hcn[q][1]);
  }

  // ---- next-layer pre-LN: uout = relu(LN(hc)) ----
  if (writeU) {
#pragma unroll
    for (int q = 0; q < 2; q++) {
      sPs[jg * 16 + n0 + q] = hcn[q][0] + hcn[q][1];
      sPq[jg * 16 + n0 + q] = hcn[q][0] * hcn[q][0] + hcn[q][1] * hcn[q][1];
    }
    __syncthreads();  // B4
    if (tid < TILE) {
      float s = 0.f, qq = 0.f;
      for (int g = 0; g < 32; g++) { s += sPs[g * 16 + tid]; qq += sPq[g * 16 + tid]; }
      float mu = s * (1.f / 64.f);
      float var = qq * (1.f / 64.f) - mu * mu;
      sMu[tid] = mu;
      sRs[tid] = rsqrtf(var + 1e-5f);
    }
    __syncthreads();  // B5
    float2 lgv = *((const float2*)&lng[o0]);
    float2 lbv = *((const float2*)&lnb[o0]);
#pragma unroll
    for (int q = 0; q < 2; q++) {
      int gn = t0 + n0 + q;
      float mu = sMu[n0 + q], rs = sRs[n0 + q];
      float2 uvv;
      uvv.x = fmaxf((hcn[q][0] - mu) * rs * lgv.x + lbv.x, 0.f);
      uvv.y = fmaxf((hcn[q][1] - mu) * rs * lgv.y + lbv.y, 0.f);
      *((float2*)&uout[gn * 64 + o0]) = uvv;
    }
  }
}

// ---------------- final: out = relu(LN(hc, g0, b0)) @ W_out + b_out ----------------

__global__ __launch_bounds__(256) void k_final(const float* __restrict__ hc, const float* __restrict__ g,
                                               const float* __restrict__ bptr, const float* __restrict__ Wout,
                                               const float* __restrict__ bout, float* __restrict__ out) {
  __shared__ float sW[DIM * DIM];
  int tid = threadIdx.x;
  for (int i = tid; i < 1024; i += 256) ((float4*)sW)[i] = ((const float4*)Wout)[i];
  __syncthreads();
  int lane = tid & 63, w = tid >> 6;
  int n = blockIdx.x * 4 + w;
  if (n >= N_NODES) return;
  float v = hc[n * 64 + lane];
  float s = v, q = v * v;
#pragma unroll
  for (int o = 32; o; o >>= 1) { s += __shfl_xor(s, o); q += __shfl_xor(q, o); }
  float mu = s * (1.f / 64.f);
  float var = q * (1.f / 64.f) - mu * mu;
  float rs = rsqrtf(var + 1e-5f);
  float z = fmaxf((v - mu) * rs * g[lane] + bptr[lane], 0.f);
  float acc = bout[lane];
  for (int k = 0; k < 64; k++) {
    float zk = __shfl(z, k);
    acc += zk * sW[k * 64 + lane];
  }
  out[n * 64 + lane] = acc;
}

// ---------------- host ----------------

extern "C" void kernel_launch(void* const* d_in, const int* in_sizes, int n_in,
                              void* d_out, int out_size, void* d_ws, size_t ws_size,
                              hipStream_t stream) {
  const float* x        = (const float*)d_in[0];
  const float* eattr    = (const float*)d_in[1];
  const int*   src      = (const int*)d_in[2];
  const int*   dst      = (const int*)d_in[3];
  const float* W_node   = (const float*)d_in[4];
  const float* b_node   = (const float*)d_in[5];
  const float* W_edge   = (const float*)d_in[6];
  const float* b_edge   = (const float*)d_in[7];
  const float* t        = (const float*)d_in[8];
  const float* W1       = (const float*)d_in[9];
  const float* b1       = (const float*)d_in[10];
  const float* g1       = (const float*)d_in[11];
  const float* be1      = (const float*)d_in[12];
  const float* W2       = (const float*)d_in[13];
  const float* b2       = (const float*)d_in[14];
  const float* ln_g     = (const float*)d_in[15];
  const float* ln_b     = (const float*)d_in[16];
  const float* W_out    = (const float*)d_in[17];
  const float* b_out    = (const float*)d_in[18];
  float* out = (float*)d_out;

  char* w = (char*)d_ws;
  float* uA      = (float*)w;  w += (size_t)N_NODES * 64 * 4;
  float* uB      = (float*)w;  w += (size_t)N_NODES * 64 * 4;
  float* hcb     = (float*)w;  w += (size_t)N_NODES * 64 * 4;
  int* off       = (int*)w;    w += (size_t)(N_NODES + 1) * 4;
  int* cur       = (int*)w;    w += (size_t)N_NODES * 4;
  int* eids      = (int*)w;    w += (size_t)N_EDGES * 4;
  int* src_s     = (int*)w;    w += (size_t)N_EDGES * 4;
  float4* eattr_s = (float4*)w; w += (size_t)N_EDGES * 16;

  // CSR build (deterministic: per-node bitonic sort by edge id fixes slot order)
  k_zero<<<(N_NODES + 255) / 256, 256, 0, stream>>>(cur, N_NODES);
  k_hist<<<(N_EDGES + 255) / 256, 256, 0, stream>>>(dst, cur);
  k_scan<<<1, 256, 0, stream>>>(cur, off);
  k_scatter<<<(N_EDGES + 255) / 256, 256, 0, stream>>>(dst, cur, eids);
  k_sortgather<<<(N_NODES + 3) / 4, 256, 0, stream>>>(off, eids, src, (const float4*)eattr,
                                                      src_s, eattr_s);

  // node encoder -> hc and uA (layer-0 input)
  k_enc<<<(N_NODES * 64 + 255) / 256, 256, 0, stream>>>(x, W_node, b_node, hcb, uA);

  for (int l = 0; l < LAYERS; l++) {
    const float* uin = (l & 1) ? uB : uA;
    float* uo        = (l & 1) ? uA : uB;
    int nxt = (l + 1 < LAYERS) ? (l + 1) : 0;  // unused when writeU=0
    k_layer<<<NBLK, 256, 0, stream>>>(uin, hcb, uo, eattr_s, src_s, off,
                                      W_edge, b_edge, t, l,
                                      W1 + (size_t)l * DIM * HID, b1 + (size_t)l * HID,
                                      g1 + (size_t)l * HID, be1 + (size_t)l * HID,
                                      W2 + (size_t)l * HID * DIM, b2 + (size_t)l * DIM,
                                      ln_g + (size_t)nxt * DIM, ln_b + (size_t)nxt * DIM,
                                      (l > 0) ? 1 : 0, (l < LAYERS - 1) ? 1 : 0);
  }

  k_final<<<(N_NODES + 3) / 4, 256, 0, stream>>>(hcb, ln_g, ln_b, W_out, b_out, out);
}